// Round 23
// baseline (166.104 us; speedup 1.0000x reference)
//
#include <hip/hip_runtime.h>
#include <cstdint>
#include <cstddef>

// ---------- types ----------
typedef __attribute__((ext_vector_type(8))) short short8;   // 8 x bf16 (4 VGPR)
typedef __attribute__((ext_vector_type(4))) float f32x4;

#define LOG2E 1.4426950408889634f
#define LN2   0.6931471805599453f
#define RSTR  144   // red row stride (floats); 144%32=16 -> 2-way bank alias (free)

// raw v_exp_f32 (1 instr): inputs bounded, -inf -> 0 in HW.
#define EXP2R(x) __builtin_amdgcn_exp2f(x)

__device__ __forceinline__ unsigned short f2bf(float x) {
    unsigned u = __float_as_uint(x);
    u += 0x7FFFu + ((u >> 16) & 1u);        // RNE
    return (unsigned short)(u >> 16);
}
__device__ __forceinline__ float bf2f(unsigned short h) {
    return __uint_as_float(((unsigned)h) << 16);
}

// async global->LDS, 16B per lane; LDS dest = uniform base + lane*16
__device__ __forceinline__ void gload_lds16(const void* g, void* l) {
    __builtin_amdgcn_global_load_lds(
        (const __attribute__((address_space(1))) unsigned int*)g,
        (__attribute__((address_space(3))) unsigned int*)l, 16, 0, 0);
}

// per-lane 16-logit partial sum of exp2 (max-free LSE; bias=-inf rows -> 0).
__device__ __forceinline__ float sum16p(const f32x4 (&accv)[4][4], int ni,
                                        const float (&bvv)[4][4]) {
    float e[16];
#pragma unroll
    for (int q = 0; q < 16; ++q)
        e[q] = EXP2R(fmaf(accv[q >> 2][ni][q & 3], LOG2E, bvv[q >> 2][q & 3]));
#pragma unroll
    for (int st = 1; st < 16; st <<= 1)
#pragma unroll
        for (int q = 0; q < 16; q += st * 2)
            e[q] += e[q + st];
    return e[0];
}

// ---------- kernel 1: fused f32->bf16 conversion ----------
// Whb UNIFIED [20096][1024]: W_head 0..19999, W_clu 20000..20002, zeros to 20095.
__global__ void mega_convert(const float* __restrict__ hidden,
                             const float* __restrict__ P1, const float* __restrict__ P2,
                             const float* __restrict__ P3,
                             const float* __restrict__ W_head, const float* __restrict__ W_clu,
                             unsigned short* __restrict__ hbf, unsigned short* __restrict__ Pb,
                             unsigned short* __restrict__ Whb,
                             int nWh, int nClu, int nZp) {
    long i = (long)blockIdx.x * 256 + threadIdx.x;
    const float* src;
    unsigned short* dst;
    if (i < nWh)                      { src = W_head; dst = Whb; }
    else if ((i -= nWh) < nClu)       { src = W_clu;  dst = Whb + (size_t)20000 * 1024; }
    else if ((i -= nClu) < nZp) {
        *(unsigned long long*)(Whb + (size_t)20003 * 1024 + i * 4) = 0ull;
        return;
    }
    else if ((i -= nZp) < 262144)     { src = hidden; dst = hbf; }
    else if ((i -= 262144) < 65536)   { src = P1;     dst = Pb; }
    else if ((i -= 65536) < 16384)    { src = P2;     dst = Pb + (size_t)256 * 1024; }
    else if ((i -= 16384) < 4096)     { src = P3;     dst = Pb + (size_t)320 * 1024; }
    else if ((i -= 4096) < 12288) {
        *(unsigned long long*)(Pb + (size_t)336 * 1024 + i * 4) = 0ull;
        return;
    } else return;
    float4 v = *(const float4*)(src + (size_t)i * 4);
    unsigned long long p = (unsigned long long)f2bf(v.x)
                         | ((unsigned long long)f2bf(v.y) << 16)
                         | ((unsigned long long)f2bf(v.z) << 32)
                         | ((unsigned long long)f2bf(v.w) << 48);
    *(unsigned long long*)(dst + (size_t)i * 4) = p;
}

// ---------- kernel 2: deterministic cluster compaction (1 block, 1024 threads) ----------
__global__ __launch_bounds__(1024)
void compact_tokens(const int* __restrict__ target, int* __restrict__ cnt,
                    int* __restrict__ slotc) {
    const int t = threadIdx.x;
    const int tgt = target[t];
    const int cid = (tgt >= 20000) + (tgt >= 40000) + (tgt >= 200000);
    const int wave = t >> 6, lane = t & 63;
    unsigned long long lt = (lane == 0) ? 0ull : (~0ull >> (64 - lane));
    __shared__ int wtot[3][16];
    __shared__ int wbase[3][16];
    unsigned long long bal[3];
#pragma unroll
    for (int c = 1; c <= 3; ++c) {
        unsigned long long b = __ballot(cid == c);
        if (lane == 0) wtot[c - 1][wave] = (int)__popcll(b);
        bal[c - 1] = b;
    }
    __syncthreads();
    if (t < 3) {
        int s = 0;
        for (int w = 0; w < 16; ++w) { wbase[t][w] = s; s += wtot[t][w]; }
        cnt[t + 1] = s;
        if (t == 0) cnt[0] = 1024;
    }
    __syncthreads();
    int sl = t;
    if (cid > 0) sl = wbase[cid - 1][wave] + (int)__popcll(bal[cid - 1] & lt);
    slotc[t] = sl | (cid << 16);
}

// ---------- kernel 3: MFMA projection, writes DIRECTLY into compacted Hc buffers ----------
__global__ __launch_bounds__(256)
void proj_mfma(const unsigned short* __restrict__ Hb,   // [1024][1024]
               const unsigned short* __restrict__ Pb,   // [384][1024]
               const int* __restrict__ slotc,
               unsigned short* __restrict__ Hc1,        // [1024][256] compacted
               unsigned short* __restrict__ Hc2,        // [1024][64]
               unsigned short* __restrict__ Hc3) {      // [1024][64]
    __shared__ __align__(16) char As[16384];
    __shared__ __align__(16) char Bs[16384];
    __shared__ int sl_s[128];
    const int tid  = threadIdx.x;
    const int lane = tid & 63;
    const int wid  = tid >> 6;
    const int wm = wid >> 1, wn = wid & 1;
    const int tt = blockIdx.x, dt = blockIdx.y;
    const int t0 = tt * 128, d0 = dt * 128;

    f32x4 acc[4][4];
    const f32x4 zero = {0.f, 0.f, 0.f, 0.f};
#pragma unroll
    for (int i = 0; i < 4; ++i)
#pragma unroll
        for (int j = 0; j < 4; ++j) acc[i][j] = zero;

    const unsigned short* asrc[4];
    const unsigned short* bsrc[4];
    int ldst[4];
#pragma unroll
    for (int j = 0; j < 4; ++j) {
        int lds_off = wid * 4096 + j * 1024;
        int o = lds_off + lane * 16;
        int r = o >> 7;
        int b = (o & 127) ^ ((r & 7) << 4);
        ldst[j] = lds_off;
        asrc[j] = Hb + (size_t)(t0 + r) * 1024 + (b >> 1);
        bsrc[j] = Pb + (size_t)(d0 + r) * 1024 + (b >> 1);
    }

    for (int kt = 0; kt < 16; ++kt) {
#pragma unroll
        for (int j = 0; j < 4; ++j) gload_lds16(asrc[j] + kt * 64, As + ldst[j]);
#pragma unroll
        for (int j = 0; j < 4; ++j) gload_lds16(bsrc[j] + kt * 64, Bs + ldst[j]);
        __syncthreads();
#pragma unroll
        for (int kk = 0; kk < 2; ++kk) {
            const int kbyte = (kk * 32 + ((lane >> 4) << 3)) * 2;
            short8 a[4], b[4];
#pragma unroll
            for (int mi = 0; mi < 4; ++mi) {
                int row = wm * 64 + mi * 16 + (lane & 15);
                int off = row * 128 + (kbyte ^ ((row & 7) << 4));
                a[mi] = *(const short8*)(As + off);
            }
#pragma unroll
            for (int ni = 0; ni < 4; ++ni) {
                int row = wn * 64 + ni * 16 + (lane & 15);
                int off = row * 128 + (kbyte ^ ((row & 7) << 4));
                b[ni] = *(const short8*)(Bs + off);
            }
#pragma unroll
            for (int mi = 0; mi < 4; ++mi)
#pragma unroll
                for (int ni = 0; ni < 4; ++ni)
                    acc[mi][ni] = __builtin_amdgcn_mfma_f32_16x16x32_bf16(a[mi], b[ni], acc[mi][ni], 0, 0, 0);
        }
        __syncthreads();
    }

    if (tid < 128) sl_s[tid] = slotc[t0 + tid];
    __syncthreads();

#pragma unroll
    for (int ni = 0; ni < 4; ++ni) {
        int dg = d0 + wn * 64 + ni * 16 + (lane & 15);
        unsigned short* base;
        int c_d, dd, stride;
        if (dg < 256)      { c_d = 1; dd = dg;       base = Hc1; stride = 256; }
        else if (dg < 320) { c_d = 2; dd = dg - 256; base = Hc2; stride = 64;  }
        else               { c_d = 3; dd = dg - 320; base = Hc3; stride = 64;  }
#pragma unroll
        for (int mi = 0; mi < 4; ++mi)
#pragma unroll
            for (int r = 0; r < 4; ++r) {
                int tl = wm * 64 + mi * 16 + ((lane >> 4) << 2) + r;
                int sc = sl_s[tl];
                if ((sc >> 16) == c_d)
                    base[(size_t)(sc & 0xFFFF) * stride + dd] = f2bf(acc[mi][ni][r]);
            }
    }
}

// ---------- device body: 128x128 GEMM + max-free LSE; atomic S accumulation ----------
// red layout: [8][RSTR]
template<bool BF16B>
__device__ __forceinline__ void gemm_lse_dev(
        char* Ws, char* Hs, float* bias_s, float* red,
        const unsigned short* __restrict__ Wb,
        const float* __restrict__ Wfa, const float* __restrict__ Wfb,
        int NsplitW, int NsplitB, int N, int K, int Kv, int KTILES,
        const float* __restrict__ bias1, const float* __restrict__ bias2,
        const unsigned short* __restrict__ H, int t0, int n0,
        float* __restrict__ pT) {                    // atomicAdd target [tokens]
    const int tid  = threadIdx.x;
    const int lane = tid & 63;
    const int wid  = tid >> 6;
    const int wm = wid >> 1, wn = wid & 1;
    const bool clean = BF16B && (n0 + 128 <= NsplitW);

    if (tid < 128) {
        int v = n0 + tid;
        bias_s[tid] = (v < NsplitB) ? bias1[v] * LOG2E
                    : (v < N)       ? bias2[v - NsplitB] * LOG2E
                                    : -INFINITY;
    }

    f32x4 acc[4][4];
    const f32x4 zero = {0.f, 0.f, 0.f, 0.f};
#pragma unroll
    for (int i = 0; i < 4; ++i)
#pragma unroll
        for (int j = 0; j < 4; ++j) acc[i][j] = zero;

    const unsigned short* wsrc[4];
    const unsigned short* hsrc[4];
    int ldst[4];
#pragma unroll
    for (int j = 0; j < 4; ++j) {
        int lds_off = wid * 4096 + j * 1024;
        int o = lds_off + lane * 16;
        int r = o >> 7;
        int b = (o & 127) ^ ((r & 7) << 4);
        ldst[j] = lds_off;
        hsrc[j] = H + (size_t)(t0 + r) * K + (b >> 1);
        wsrc[j] = clean ? (Wb + (size_t)(n0 + r) * K + (b >> 1)) : nullptr;
    }
    int arow[4], brow[4];
#pragma unroll
    for (int q = 0; q < 4; ++q) {
        arow[q] = wm * 64 + q * 16 + (lane & 15);
        brow[q] = wn * 64 + q * 16 + (lane & 15);
    }
    const int kbase = (lane >> 4) << 4;

    for (int kt = 0; kt < KTILES; ++kt) {
        if (clean) {
#pragma unroll
            for (int j = 0; j < 4; ++j) gload_lds16(wsrc[j] + kt * 64, Ws + ldst[j]);
        } else {
#pragma unroll
            for (int it = 0; it < 4; ++it) {
                int c = tid + it * 256;
                int row = c >> 3, kc = (c & 7) << 3;
                int v = n0 + row;
                int kg = kt * 64 + kc;
                unsigned short hh[8] = {0,0,0,0,0,0,0,0};
                if (v < NsplitB) {
                    if (BF16B) {
                        *(int4*)hh = *(const int4*)(Wb + (size_t)v * K + kg);
                    } else if (kg + 8 <= Kv) {
                        const float* p = Wfa + (size_t)v * Kv;
                        float4 u0 = *(const float4*)(p + kg);
                        float4 u1 = *(const float4*)(p + kg + 4);
                        hh[0]=f2bf(u0.x); hh[1]=f2bf(u0.y); hh[2]=f2bf(u0.z); hh[3]=f2bf(u0.w);
                        hh[4]=f2bf(u1.x); hh[5]=f2bf(u1.y); hh[6]=f2bf(u1.z); hh[7]=f2bf(u1.w);
                    }
                } else if (v < N && Wfb != nullptr) {
                    const float* p = Wfb + (size_t)(v - NsplitB) * K;
                    float4 u0 = *(const float4*)(p + kg);
                    float4 u1 = *(const float4*)(p + kg + 4);
                    hh[0]=f2bf(u0.x); hh[1]=f2bf(u0.y); hh[2]=f2bf(u0.z); hh[3]=f2bf(u0.w);
                    hh[4]=f2bf(u1.x); hh[5]=f2bf(u1.y); hh[6]=f2bf(u1.z); hh[7]=f2bf(u1.w);
                }
                int off = (row * 128 + kc * 2) ^ ((row & 7) << 4);
                *(int4*)(Ws + off) = *(const int4*)hh;
            }
        }
#pragma unroll
        for (int j = 0; j < 4; ++j) gload_lds16(hsrc[j] + kt * 64, Hs + ldst[j]);
        __syncthreads();
#pragma unroll
        for (int kk = 0; kk < 2; ++kk) {
            const int kbyte = kk * 64 + kbase;
            short8 a[4], b[4];
#pragma unroll
            for (int mi = 0; mi < 4; ++mi)
                a[mi] = *(const short8*)(Ws + arow[mi] * 128 + (kbyte ^ ((arow[mi] & 7) << 4)));
#pragma unroll
            for (int ni = 0; ni < 4; ++ni)
                b[ni] = *(const short8*)(Hs + brow[ni] * 128 + (kbyte ^ ((brow[ni] & 7) << 4)));
#pragma unroll
            for (int mi = 0; mi < 4; ++mi)
#pragma unroll
                for (int ni = 0; ni < 4; ++ni)
                    acc[mi][ni] = __builtin_amdgcn_mfma_f32_16x16x32_bf16(a[mi], b[ni], acc[mi][ni], 0, 0, 0);
        }
        __syncthreads();
    }

    float bvv[4][4];
#pragma unroll
    for (int mi = 0; mi < 4; ++mi)
#pragma unroll
        for (int r = 0; r < 4; ++r)
            bvv[mi][r] = bias_s[wm * 64 + mi * 16 + ((lane >> 4) << 2) + r];

    const int gslot = (wm * 4 + (lane >> 4)) * RSTR + wn * 64 + (lane & 15);
#pragma unroll
    for (int ni = 0; ni < 4; ++ni)
        red[gslot + ni * 16] = sum16p(acc, ni, bvv);
    __syncthreads();
    if (tid < 128) {
        float s = 0.f;
#pragma unroll
        for (int g = 0; g < 8; ++g) s += red[g * RSTR + tid];
        atomicAdd(&pT[t0 + tid], s);
    }
}

// ---------- device body: W-resident tail GEMM (K<=64), BARRIER-FREE token loop ----------
// B fragments read directly from global (Hc is L2-resident; no Hs staging, no
// barriers after the initial W stage). Intra-wave 2-shuffle combine + atomicAdd.
template<int KV>
__device__ __forceinline__ void tail_res_dev(
        char* Ws, float* bias_s,
        const float* __restrict__ Wf, int N,
        const float* __restrict__ bias,
        const unsigned short* __restrict__ Hc, int cntc, int n0,
        float* __restrict__ pT) {
    const int tid = threadIdx.x, lane = tid & 63, wid = tid >> 6;
    const int wm = wid >> 1, wn = wid & 1;

    // ---- stage W once: f32 -> bf16, swizzled, zero-pad k>=KV ----
#pragma unroll
    for (int it = 0; it < 4; ++it) {
        int c = tid + it * 256;
        int row = c >> 3, kc = (c & 7) << 3;
        int v = n0 + row;
        unsigned short hh[8] = {0,0,0,0,0,0,0,0};
        if (v < N && kc < KV) {
            const float* p = Wf + (size_t)v * KV + kc;
            float4 u0 = *(const float4*)p;
            float4 u1 = *(const float4*)(p + 4);
            hh[0]=f2bf(u0.x); hh[1]=f2bf(u0.y); hh[2]=f2bf(u0.z); hh[3]=f2bf(u0.w);
            hh[4]=f2bf(u1.x); hh[5]=f2bf(u1.y); hh[6]=f2bf(u1.z); hh[7]=f2bf(u1.w);
        }
        int off = (row * 128 + kc * 2) ^ ((row & 7) << 4);
        *(int4*)(Ws + off) = *(const int4*)hh;
    }
    if (tid < 128) {
        int v = n0 + tid;
        bias_s[tid] = (v < N) ? bias[v] * LOG2E : -INFINITY;
    }
    __syncthreads();    // the ONLY barrier in this body
    short8 a[2][4];
#pragma unroll
    for (int kk = 0; kk < 2; ++kk)
#pragma unroll
        for (int mi = 0; mi < 4; ++mi) {
            int row = wm * 64 + mi * 16 + (lane & 15);
            int kbyte = (kk * 32 + ((lane >> 4) << 3)) * 2;
            a[kk][mi] = *(const short8*)(Ws + ((row * 128 + kbyte) ^ ((row & 7) << 4)));
        }
    float bvv[4][4];
#pragma unroll
    for (int mi = 0; mi < 4; ++mi)
#pragma unroll
        for (int r = 0; r < 4; ++r)
            bvv[mi][r] = bias_s[wm * 64 + mi * 16 + ((lane >> 4) << 2) + r];
    const int ntt = (cntc + 127) >> 7;

    // per-lane direct-global B bases: token row = wn*64 + ni*16 + (lane&15),
    // k chunk = kk*32 + (lane>>4)*8  (4 groups cover a contiguous 64B row-half)
    const unsigned short* hrow[4];
#pragma unroll
    for (int ni = 0; ni < 4; ++ni)
        hrow[ni] = Hc + (size_t)(wn * 64 + ni * 16 + (lane & 15)) * 64
                 + ((lane >> 4) << 3);
    const int tok0 = wn * 64 + (lane & 15);

    for (int tt = 0; tt < ntt; ++tt) {
        const int radv = tt * 8192;   // 128 rows * 64 elems
        f32x4 acc[4][4];
        const f32x4 zero = {0.f, 0.f, 0.f, 0.f};
#pragma unroll
        for (int i = 0; i < 4; ++i)
#pragma unroll
            for (int j = 0; j < 4; ++j) acc[i][j] = zero;
#pragma unroll
        for (int kk = 0; kk < 2; ++kk) {
            short8 b[4];
#pragma unroll
            for (int ni = 0; ni < 4; ++ni)
                b[ni] = *(const short8*)(hrow[ni] + radv + kk * 32);
#pragma unroll
            for (int mi = 0; mi < 4; ++mi)
#pragma unroll
                for (int ni = 0; ni < 4; ++ni)
                    acc[mi][ni] = __builtin_amdgcn_mfma_f32_16x16x32_bf16(a[kk][mi], b[ni], acc[mi][ni], 0, 0, 0);
        }
        // intra-wave combine (tokens invariant under xor 16/32) + atomic
#pragma unroll
        for (int ni = 0; ni < 4; ++ni) {
            float sm = sum16p(acc, ni, bvv);
            sm += __shfl_xor(sm, 16, 64);
            sm += __shfl_xor(sm, 32, 64);
            if ((lane >> 4) == 0)
                atomicAdd(&pT[tt * 128 + tok0 + ni * 16], sm);
        }
    }
}

// ---------- kernel 4: FUSED head + tails, TYPE-INTERLEAVED schedule ----------
#define NSLOT 435
template<bool PRE>
__global__ __launch_bounds__(256)
void fused_lse(const unsigned short* __restrict__ Whb,   // [20096][1024] unified
               const float* __restrict__ W_head, const float* __restrict__ W_clu,
               const float* __restrict__ W1,
               const float* __restrict__ W2, const float* __restrict__ W3,
               const float* __restrict__ b_head, const float* __restrict__ b_clu,
               const float* __restrict__ b1, const float* __restrict__ b2,
               const float* __restrict__ b3,
               const unsigned short* __restrict__ hbf,
               const unsigned short* __restrict__ Hc1,
               const unsigned short* __restrict__ Hc2,
               const unsigned short* __restrict__ Hc3,
               const int* __restrict__ cnt,
               float* __restrict__ pT) {                 // [4][1024] zeroed totals
    __shared__ __align__(16) char smem[37888];
    char* Ws = smem;
    char* Hs = smem + 16384;
    float* bias_s = (float*)(smem + 32768);
    float* red    = (float*)(smem + 33280);   // [8][RSTR] = 4608B
    const int b = blockIdx.x;
    const int x = b & 7;
    const int i = b >> 3;
    const int m = i % 5, j = i / 5;

    if (m == 0 || m == 2) {
        const int h = 2 * j + (m >> 1);
        if (h >= 160) return;
        const int nt = x * 20 + (h >> 3);
        const int tt = h & 7;
        if (nt >= 157) return;
        if (PRE)
            gemm_lse_dev<true>(Ws, Hs, bias_s, red,
                               Whb, nullptr, nullptr,
                               20096, 20000, 20003, 1024, 1024, 16,
                               b_head, b_clu, hbf, tt * 128, nt * 128, pT);
        else
            gemm_lse_dev<false>(Ws, Hs, bias_s, red,
                                nullptr, W_head, W_clu,
                                20000, 20000, 20003, 1024, 1024, 16,
                                b_head, b_clu, hbf, tt * 128, nt * 128, pT);
    } else if (m == 1 || m == 3) {
        const int v = (2 * j + ((m - 1) >> 1)) * 8 + x;
        if (v >= 1250) return;
        tail_res_dev<64>(Ws, bias_s, W2, 160000, b2,
                         Hc2, cnt[2], v * 128, pT + 2 * 1024);
    } else {
        if (j < 67) {
            const int v = j * 8 + x;
            if (v >= 530) return;
            tail_res_dev<16>(Ws, bias_s, W3, 67735, b3,
                             Hc3, cnt[3], v * 128, pT + 3 * 1024);
        } else {
            const int nt = (j - 67) * 8 + x;
            if (nt >= 157) return;
            const int c1 = cnt[1];
            for (int t0 = 0; t0 < c1; t0 += 128)
                gemm_lse_dev<false>(Ws, Hs, bias_s, red,
                                    nullptr, W1, nullptr,
                                    20000, 20000, 20000, 256, 256, 4,
                                    b1, nullptr, Hc1, t0, nt * 128, pT + 1 * 1024);
        }
    }
}

// ---------- kernel 5: finalize (gather + assemble; reads atomic totals) ----------
__global__ void finalize(const float* __restrict__ hidden, const int* __restrict__ target,
                         const float* __restrict__ W_head, const float* __restrict__ b_head,
                         const float* __restrict__ W_clu, const float* __restrict__ b_clu,
                         const float* __restrict__ W1, const float* __restrict__ b1,
                         const float* __restrict__ W2, const float* __restrict__ b2,
                         const float* __restrict__ W3, const float* __restrict__ b3,
                         const unsigned short* __restrict__ Hc1,
                         const unsigned short* __restrict__ Hc2,
                         const unsigned short* __restrict__ Hc3,
                         const int* __restrict__ slotc,
                         const float* __restrict__ pT,    // [4][1024]
                         float* __restrict__ out) {
    const int t = blockIdx.x;
    const int lane = threadIdx.x;
    const int tgt = target[t];
    const int cid = (tgt >= 20000) + (tgt >= 40000) + (tgt >= 200000);
    const int slot = slotc[t] & 0xFFFF;

    float lse0 = LN2 * log2f(pT[t]);
    float lsec = (cid > 0) ? LN2 * log2f(pT[cid * 1024 + slot]) : 0.f;

    const int j = (cid == 0) ? tgt : (20003 - cid);
    const float* wr = (j < 20000) ? (W_head + (size_t)j * 1024)
                                  : (W_clu + (size_t)(j - 20000) * 1024);
    float acc = 0.f;
#pragma unroll
    for (int i = 0; i < 4; ++i) {
        int k4 = lane + i * 64;
        float4 h = *(const float4*)(hidden + (size_t)t * 1024 + k4 * 4);
        float4 w = *(const float4*)(wr + k4 * 4);
        acc += h.x * w.x + h.y * w.y + h.z * w.z + h.w * w.w;
    }
#pragma unroll
    for (int msk = 1; msk < 64; msk <<= 1) acc += __shfl_xor(acc, msk, 64);
    float bj = (j < 20000) ? b_head[j] : b_clu[j - 20000];
    float res = (acc + bj) - lse0;
    if (cid > 0) {
        const int starts[4] = {0, 20000, 40000, 200000};
        const int dims[4]   = {0, 256, 64, 16};
        const float* Wt = (cid == 1) ? W1 : (cid == 2) ? W2 : W3;
        const float* bt = (cid == 1) ? b1 : (cid == 2) ? b2 : b3;
        const unsigned short* pr = (cid == 1) ? Hc1 + (size_t)slot * 256
                                 : (cid == 2) ? Hc2 + (size_t)slot * 64
                                              : Hc3 + (size_t)slot * 64;
        int ti = tgt - starts[cid];
        int d  = dims[cid];
        const float* wt = Wt + (size_t)ti * d;
        float a2 = 0.f;
        for (int k = lane; k < d; k += 64) a2 += bf2f(pr[k]) * wt[k];
#pragma unroll
        for (int msk = 1; msk < 64; msk <<= 1) a2 += __shfl_xor(a2, msk, 64);
        res += (a2 + bt[ti]) - lsec;
    }
    if (lane == 0) out[t] = -res;
}

// ---------- launch ----------
extern "C" void kernel_launch(void* const* d_in, const int* in_sizes, int n_in,
                              void* d_out, int out_size, void* d_ws, size_t ws_size,
                              hipStream_t stream) {
    const float* hidden = (const float*)d_in[0];
    const int*   target = (const int*)d_in[1];
    const float* W_head = (const float*)d_in[2];
    const float* b_head = (const float*)d_in[3];
    const float* W_clu  = (const float*)d_in[4];
    const float* b_clu  = (const float*)d_in[5];
    const float* P1 = (const float*)d_in[6];
    const float* W1 = (const float*)d_in[7];
    const float* b1 = (const float*)d_in[8];
    const float* P2 = (const float*)d_in[9];
    const float* W2 = (const float*)d_in[10];
    const float* b2 = (const float*)d_in[11];
    const float* P3 = (const float*)d_in[12];
    const float* W3 = (const float*)d_in[13];
    const float* b3 = (const float*)d_in[14];
    float* out = (float*)d_out;

    char* ws = (char*)d_ws;
    size_t off = 0;
    auto alloc = [&](size_t bytes) -> char* {
        char* p = ws + off;
        off += (bytes + 255) & ~(size_t)255;
        return p;
    };

    unsigned short* hbf   = (unsigned short*)alloc((size_t)1024 * 1024 * 2);
    unsigned short* Pb    = (unsigned short*)alloc((size_t)384 * 1024 * 2);
    int* cnt   = (int*)alloc(4 * 4);
    int* slotc = (int*)alloc(1024 * 4);
    unsigned short* Hc1 = (unsigned short*)alloc((size_t)1024 * 256 * 2);
    unsigned short* Hc2 = (unsigned short*)alloc((size_t)1024 * 64 * 2);
    unsigned short* Hc3 = (unsigned short*)alloc((size_t)1024 * 64 * 2);
    float* pT  = (float*)alloc((size_t)4 * 1024 * 4);
    unsigned short* Whb = (unsigned short*)alloc((size_t)20096 * 1024 * 2);  // unified + pad
    const bool pre = (off <= ws_size);

    const int nWh  = pre ? 5120000 : 0;   // W_head chunks
    const int nClu = pre ? 768 : 0;       // W_clu chunks
    const int nZp  = pre ? 23808 : 0;     // zero rows 20003..20095
    const long nChunks = (long)nWh + nClu + nZp + 360448;
    mega_convert<<<(unsigned)((nChunks + 255) / 256), 256, 0, stream>>>(
        hidden, P1, P2, P3, W_head, W_clu, hbf, Pb, Whb, nWh, nClu, nZp);
    compact_tokens<<<1, 1024, 0, stream>>>(target, cnt, slotc);
    (void)hipMemsetAsync(pT, 0, (size_t)4 * 1024 * 4, stream);
    proj_mfma<<<dim3(8, 3), 256, 0, stream>>>(hbf, Pb, slotc, Hc1, Hc2, Hc3);

    const int NB_TOT = 8 * NSLOT;   // 3480, type-interleaved
    if (pre)
        fused_lse<true><<<NB_TOT, 256, 0, stream>>>(
            Whb, W_head, W_clu, W1, W2, W3,
            b_head, b_clu, b1, b2, b3,
            hbf, Hc1, Hc2, Hc3, cnt, pT);
    else
        fused_lse<false><<<NB_TOT, 256, 0, stream>>>(
            Whb, W_head, W_clu, W1, W2, W3,
            b_head, b_clu, b1, b2, b3,
            hbf, Hc1, Hc2, Hc3, cnt, pT);

    finalize<<<1024, 64, 0, stream>>>(hidden, target,
                                      W_head, b_head, W_clu, b_clu,
                                      W1, b1, W2, b2, W3, b3,
                                      Hc1, Hc2, Hc3, slotc, pT, out);
}

// Round 24
// 148.809 us; speedup vs baseline: 1.1162x; 1.1162x over previous
//
#include <hip/hip_runtime.h>
#include <cstdint>
#include <cstddef>

// ---------- types ----------
typedef __attribute__((ext_vector_type(8))) short short8;   // 8 x bf16 (4 VGPR)
typedef __attribute__((ext_vector_type(4))) float f32x4;

#define LOG2E 1.4426950408889634f
#define LN2   0.6931471805599453f
#define RSTR  144   // red row stride (floats); 144%32=16 -> 2-way bank alias (free)

// raw v_exp_f32 (1 instr): inputs bounded, -inf -> 0 in HW.
#define EXP2R(x) __builtin_amdgcn_exp2f(x)

__device__ __forceinline__ unsigned short f2bf(float x) {
    unsigned u = __float_as_uint(x);
    u += 0x7FFFu + ((u >> 16) & 1u);        // RNE
    return (unsigned short)(u >> 16);
}
__device__ __forceinline__ float bf2f(unsigned short h) {
    return __uint_as_float(((unsigned)h) << 16);
}

// async global->LDS, 16B per lane; LDS dest = uniform base + lane*16
__device__ __forceinline__ void gload_lds16(const void* g, void* l) {
    __builtin_amdgcn_global_load_lds(
        (const __attribute__((address_space(1))) unsigned int*)g,
        (__attribute__((address_space(3))) unsigned int*)l, 16, 0, 0);
}

// per-lane 16-logit partial sum of exp2 (max-free LSE; bias=-inf rows -> 0).
__device__ __forceinline__ float sum16p(const f32x4 (&accv)[4][4], int ni,
                                        const float (&bvv)[4][4]) {
    float e[16];
#pragma unroll
    for (int q = 0; q < 16; ++q)
        e[q] = EXP2R(fmaf(accv[q >> 2][ni][q & 3], LOG2E, bvv[q >> 2][q & 3]));
#pragma unroll
    for (int st = 1; st < 16; st <<= 1)
#pragma unroll
        for (int q = 0; q < 16; q += st * 2)
            e[q] += e[q + st];
    return e[0];
}

// ---------- kernel 1: fused f32->bf16 conversion ----------
// Whb UNIFIED [20096][1024]: W_head 0..19999, W_clu 20000..20002, zeros to 20095.
__global__ void mega_convert(const float* __restrict__ hidden,
                             const float* __restrict__ P1, const float* __restrict__ P2,
                             const float* __restrict__ P3,
                             const float* __restrict__ W_head, const float* __restrict__ W_clu,
                             unsigned short* __restrict__ hbf, unsigned short* __restrict__ Pb,
                             unsigned short* __restrict__ Whb,
                             int nWh, int nClu, int nZp) {
    long i = (long)blockIdx.x * 256 + threadIdx.x;
    const float* src;
    unsigned short* dst;
    if (i < nWh)                      { src = W_head; dst = Whb; }
    else if ((i -= nWh) < nClu)       { src = W_clu;  dst = Whb + (size_t)20000 * 1024; }
    else if ((i -= nClu) < nZp) {
        *(unsigned long long*)(Whb + (size_t)20003 * 1024 + i * 4) = 0ull;
        return;
    }
    else if ((i -= nZp) < 262144)     { src = hidden; dst = hbf; }
    else if ((i -= 262144) < 65536)   { src = P1;     dst = Pb; }
    else if ((i -= 65536) < 16384)    { src = P2;     dst = Pb + (size_t)256 * 1024; }
    else if ((i -= 16384) < 4096)     { src = P3;     dst = Pb + (size_t)320 * 1024; }
    else if ((i -= 4096) < 12288) {
        *(unsigned long long*)(Pb + (size_t)336 * 1024 + i * 4) = 0ull;
        return;
    } else return;
    float4 v = *(const float4*)(src + (size_t)i * 4);
    unsigned long long p = (unsigned long long)f2bf(v.x)
                         | ((unsigned long long)f2bf(v.y) << 16)
                         | ((unsigned long long)f2bf(v.z) << 32)
                         | ((unsigned long long)f2bf(v.w) << 48);
    *(unsigned long long*)(dst + (size_t)i * 4) = p;
}

// ---------- kernel 2: deterministic cluster compaction (1 block, 1024 threads) ----------
__global__ __launch_bounds__(1024)
void compact_tokens(const int* __restrict__ target, int* __restrict__ cnt,
                    int* __restrict__ slotc) {
    const int t = threadIdx.x;
    const int tgt = target[t];
    const int cid = (tgt >= 20000) + (tgt >= 40000) + (tgt >= 200000);
    const int wave = t >> 6, lane = t & 63;
    unsigned long long lt = (lane == 0) ? 0ull : (~0ull >> (64 - lane));
    __shared__ int wtot[3][16];
    __shared__ int wbase[3][16];
    unsigned long long bal[3];
#pragma unroll
    for (int c = 1; c <= 3; ++c) {
        unsigned long long b = __ballot(cid == c);
        if (lane == 0) wtot[c - 1][wave] = (int)__popcll(b);
        bal[c - 1] = b;
    }
    __syncthreads();
    if (t < 3) {
        int s = 0;
        for (int w = 0; w < 16; ++w) { wbase[t][w] = s; s += wtot[t][w]; }
        cnt[t + 1] = s;
        if (t == 0) cnt[0] = 1024;
    }
    __syncthreads();
    int sl = t;
    if (cid > 0) sl = wbase[cid - 1][wave] + (int)__popcll(bal[cid - 1] & lt);
    slotc[t] = sl | (cid << 16);
}

// ---------- kernel 3: MFMA projection, writes DIRECTLY into compacted Hc buffers ----------
__global__ __launch_bounds__(256)
void proj_mfma(const unsigned short* __restrict__ Hb,   // [1024][1024]
               const unsigned short* __restrict__ Pb,   // [384][1024]
               const int* __restrict__ slotc,
               unsigned short* __restrict__ Hc1,        // [1024][256] compacted
               unsigned short* __restrict__ Hc2,        // [1024][64]
               unsigned short* __restrict__ Hc3) {      // [1024][64]
    __shared__ __align__(16) char As[16384];
    __shared__ __align__(16) char Bs[16384];
    __shared__ int sl_s[128];
    const int tid  = threadIdx.x;
    const int lane = tid & 63;
    const int wid  = tid >> 6;
    const int wm = wid >> 1, wn = wid & 1;
    const int tt = blockIdx.x, dt = blockIdx.y;
    const int t0 = tt * 128, d0 = dt * 128;

    f32x4 acc[4][4];
    const f32x4 zero = {0.f, 0.f, 0.f, 0.f};
#pragma unroll
    for (int i = 0; i < 4; ++i)
#pragma unroll
        for (int j = 0; j < 4; ++j) acc[i][j] = zero;

    const unsigned short* asrc[4];
    const unsigned short* bsrc[4];
    int ldst[4];
#pragma unroll
    for (int j = 0; j < 4; ++j) {
        int lds_off = wid * 4096 + j * 1024;
        int o = lds_off + lane * 16;
        int r = o >> 7;
        int b = (o & 127) ^ ((r & 7) << 4);
        ldst[j] = lds_off;
        asrc[j] = Hb + (size_t)(t0 + r) * 1024 + (b >> 1);
        bsrc[j] = Pb + (size_t)(d0 + r) * 1024 + (b >> 1);
    }

    for (int kt = 0; kt < 16; ++kt) {
#pragma unroll
        for (int j = 0; j < 4; ++j) gload_lds16(asrc[j] + kt * 64, As + ldst[j]);
#pragma unroll
        for (int j = 0; j < 4; ++j) gload_lds16(bsrc[j] + kt * 64, Bs + ldst[j]);
        __syncthreads();
#pragma unroll
        for (int kk = 0; kk < 2; ++kk) {
            const int kbyte = (kk * 32 + ((lane >> 4) << 3)) * 2;
            short8 a[4], b[4];
#pragma unroll
            for (int mi = 0; mi < 4; ++mi) {
                int row = wm * 64 + mi * 16 + (lane & 15);
                int off = row * 128 + (kbyte ^ ((row & 7) << 4));
                a[mi] = *(const short8*)(As + off);
            }
#pragma unroll
            for (int ni = 0; ni < 4; ++ni) {
                int row = wn * 64 + ni * 16 + (lane & 15);
                int off = row * 128 + (kbyte ^ ((row & 7) << 4));
                b[ni] = *(const short8*)(Bs + off);
            }
#pragma unroll
            for (int mi = 0; mi < 4; ++mi)
#pragma unroll
                for (int ni = 0; ni < 4; ++ni)
                    acc[mi][ni] = __builtin_amdgcn_mfma_f32_16x16x32_bf16(a[mi], b[ni], acc[mi][ni], 0, 0, 0);
        }
        __syncthreads();
    }

    if (tid < 128) sl_s[tid] = slotc[t0 + tid];
    __syncthreads();

#pragma unroll
    for (int ni = 0; ni < 4; ++ni) {
        int dg = d0 + wn * 64 + ni * 16 + (lane & 15);
        unsigned short* base;
        int c_d, dd, stride;
        if (dg < 256)      { c_d = 1; dd = dg;       base = Hc1; stride = 256; }
        else if (dg < 320) { c_d = 2; dd = dg - 256; base = Hc2; stride = 64;  }
        else               { c_d = 3; dd = dg - 320; base = Hc3; stride = 64;  }
#pragma unroll
        for (int mi = 0; mi < 4; ++mi)
#pragma unroll
            for (int r = 0; r < 4; ++r) {
                int tl = wm * 64 + mi * 16 + ((lane >> 4) << 2) + r;
                int sc = sl_s[tl];
                if ((sc >> 16) == c_d)
                    base[(size_t)(sc & 0xFFFF) * stride + dd] = f2bf(acc[mi][ni][r]);
            }
    }
}

// ---------- device body: 128x128 GEMM + max-free LSE; atomic S accumulation ----------
// red layout: [8][RSTR]
template<bool BF16B>
__device__ __forceinline__ void gemm_lse_dev(
        char* Ws, char* Hs, float* bias_s, float* red,
        const unsigned short* __restrict__ Wb,
        const float* __restrict__ Wfa, const float* __restrict__ Wfb,
        int NsplitW, int NsplitB, int N, int K, int Kv, int KTILES,
        const float* __restrict__ bias1, const float* __restrict__ bias2,
        const unsigned short* __restrict__ H, int t0, int n0,
        float* __restrict__ pT) {                    // atomicAdd target [tokens]
    const int tid  = threadIdx.x;
    const int lane = tid & 63;
    const int wid  = tid >> 6;
    const int wm = wid >> 1, wn = wid & 1;
    const bool clean = BF16B && (n0 + 128 <= NsplitW);

    if (tid < 128) {
        int v = n0 + tid;
        bias_s[tid] = (v < NsplitB) ? bias1[v] * LOG2E
                    : (v < N)       ? bias2[v - NsplitB] * LOG2E
                                    : -INFINITY;
    }

    f32x4 acc[4][4];
    const f32x4 zero = {0.f, 0.f, 0.f, 0.f};
#pragma unroll
    for (int i = 0; i < 4; ++i)
#pragma unroll
        for (int j = 0; j < 4; ++j) acc[i][j] = zero;

    const unsigned short* wsrc[4];
    const unsigned short* hsrc[4];
    int ldst[4];
#pragma unroll
    for (int j = 0; j < 4; ++j) {
        int lds_off = wid * 4096 + j * 1024;
        int o = lds_off + lane * 16;
        int r = o >> 7;
        int b = (o & 127) ^ ((r & 7) << 4);
        ldst[j] = lds_off;
        hsrc[j] = H + (size_t)(t0 + r) * K + (b >> 1);
        wsrc[j] = clean ? (Wb + (size_t)(n0 + r) * K + (b >> 1)) : nullptr;
    }
    int arow[4], brow[4];
#pragma unroll
    for (int q = 0; q < 4; ++q) {
        arow[q] = wm * 64 + q * 16 + (lane & 15);
        brow[q] = wn * 64 + q * 16 + (lane & 15);
    }
    const int kbase = (lane >> 4) << 4;

    for (int kt = 0; kt < KTILES; ++kt) {
        if (clean) {
#pragma unroll
            for (int j = 0; j < 4; ++j) gload_lds16(wsrc[j] + kt * 64, Ws + ldst[j]);
        } else {
#pragma unroll
            for (int it = 0; it < 4; ++it) {
                int c = tid + it * 256;
                int row = c >> 3, kc = (c & 7) << 3;
                int v = n0 + row;
                int kg = kt * 64 + kc;
                unsigned short hh[8] = {0,0,0,0,0,0,0,0};
                if (v < NsplitB) {
                    if (BF16B) {
                        *(int4*)hh = *(const int4*)(Wb + (size_t)v * K + kg);
                    } else if (kg + 8 <= Kv) {
                        const float* p = Wfa + (size_t)v * Kv;
                        float4 u0 = *(const float4*)(p + kg);
                        float4 u1 = *(const float4*)(p + kg + 4);
                        hh[0]=f2bf(u0.x); hh[1]=f2bf(u0.y); hh[2]=f2bf(u0.z); hh[3]=f2bf(u0.w);
                        hh[4]=f2bf(u1.x); hh[5]=f2bf(u1.y); hh[6]=f2bf(u1.z); hh[7]=f2bf(u1.w);
                    }
                } else if (v < N && Wfb != nullptr) {
                    const float* p = Wfb + (size_t)(v - NsplitB) * K;
                    float4 u0 = *(const float4*)(p + kg);
                    float4 u1 = *(const float4*)(p + kg + 4);
                    hh[0]=f2bf(u0.x); hh[1]=f2bf(u0.y); hh[2]=f2bf(u0.z); hh[3]=f2bf(u0.w);
                    hh[4]=f2bf(u1.x); hh[5]=f2bf(u1.y); hh[6]=f2bf(u1.z); hh[7]=f2bf(u1.w);
                }
                int off = (row * 128 + kc * 2) ^ ((row & 7) << 4);
                *(int4*)(Ws + off) = *(const int4*)hh;
            }
        }
#pragma unroll
        for (int j = 0; j < 4; ++j) gload_lds16(hsrc[j] + kt * 64, Hs + ldst[j]);
        __syncthreads();
#pragma unroll
        for (int kk = 0; kk < 2; ++kk) {
            const int kbyte = kk * 64 + kbase;
            short8 a[4], b[4];
#pragma unroll
            for (int mi = 0; mi < 4; ++mi)
                a[mi] = *(const short8*)(Ws + arow[mi] * 128 + (kbyte ^ ((arow[mi] & 7) << 4)));
#pragma unroll
            for (int ni = 0; ni < 4; ++ni)
                b[ni] = *(const short8*)(Hs + brow[ni] * 128 + (kbyte ^ ((brow[ni] & 7) << 4)));
#pragma unroll
            for (int mi = 0; mi < 4; ++mi)
#pragma unroll
                for (int ni = 0; ni < 4; ++ni)
                    acc[mi][ni] = __builtin_amdgcn_mfma_f32_16x16x32_bf16(a[mi], b[ni], acc[mi][ni], 0, 0, 0);
        }
        __syncthreads();
    }

    float bvv[4][4];
#pragma unroll
    for (int mi = 0; mi < 4; ++mi)
#pragma unroll
        for (int r = 0; r < 4; ++r)
            bvv[mi][r] = bias_s[wm * 64 + mi * 16 + ((lane >> 4) << 2) + r];

    const int gslot = (wm * 4 + (lane >> 4)) * RSTR + wn * 64 + (lane & 15);
#pragma unroll
    for (int ni = 0; ni < 4; ++ni)
        red[gslot + ni * 16] = sum16p(acc, ni, bvv);
    __syncthreads();
    if (tid < 128) {
        float s = 0.f;
#pragma unroll
        for (int g = 0; g < 8; ++g) s += red[g * RSTR + tid];
        atomicAdd(&pT[t0 + tid], s);
    }
}

// ---------- device body: W-resident tail GEMM (K<=64), loops token tiles ----------
template<int KV>
__device__ __forceinline__ void tail_res_dev(
        char* Ws, char* Hs, float* bias_s, float* red,      // red: [8][RSTR]
        const float* __restrict__ Wf, int N,
        const float* __restrict__ bias,
        const unsigned short* __restrict__ Hc, int cntc, int n0,
        float* __restrict__ pT) {
    const int tid = threadIdx.x, lane = tid & 63, wid = tid >> 6;
    const int wm = wid >> 1, wn = wid & 1;

#pragma unroll
    for (int it = 0; it < 4; ++it) {
        int c = tid + it * 256;
        int row = c >> 3, kc = (c & 7) << 3;
        int v = n0 + row;
        unsigned short hh[8] = {0,0,0,0,0,0,0,0};
        if (v < N && kc < KV) {
            const float* p = Wf + (size_t)v * KV + kc;
            float4 u0 = *(const float4*)p;
            float4 u1 = *(const float4*)(p + 4);
            hh[0]=f2bf(u0.x); hh[1]=f2bf(u0.y); hh[2]=f2bf(u0.z); hh[3]=f2bf(u0.w);
            hh[4]=f2bf(u1.x); hh[5]=f2bf(u1.y); hh[6]=f2bf(u1.z); hh[7]=f2bf(u1.w);
        }
        int off = (row * 128 + kc * 2) ^ ((row & 7) << 4);
        *(int4*)(Ws + off) = *(const int4*)hh;
    }
    if (tid < 128) {
        int v = n0 + tid;
        bias_s[tid] = (v < N) ? bias[v] * LOG2E : -INFINITY;
    }
    __syncthreads();
    short8 a[2][4];
#pragma unroll
    for (int kk = 0; kk < 2; ++kk)
#pragma unroll
        for (int mi = 0; mi < 4; ++mi) {
            int row = wm * 64 + mi * 16 + (lane & 15);
            int kbyte = (kk * 32 + ((lane >> 4) << 3)) * 2;
            a[kk][mi] = *(const short8*)(Ws + ((row * 128 + kbyte) ^ ((row & 7) << 4)));
        }
    float bvv[4][4];
#pragma unroll
    for (int mi = 0; mi < 4; ++mi)
#pragma unroll
        for (int r = 0; r < 4; ++r)
            bvv[mi][r] = bias_s[wm * 64 + mi * 16 + ((lane >> 4) << 2) + r];
    const int ntt = (cntc + 127) >> 7;

    const unsigned short* hsrc[4];
    int ldst[4];
#pragma unroll
    for (int j = 0; j < 4; ++j) {
        int lds_off = wid * 4096 + j * 1024;
        int o = lds_off + lane * 16;
        int r = o >> 7;
        int b = (o & 127) ^ ((r & 7) << 4);
        ldst[j] = lds_off;
        hsrc[j] = Hc + (size_t)r * 64 + (b >> 1);
    }
    int brow[4];
#pragma unroll
    for (int q = 0; q < 4; ++q) brow[q] = wn * 64 + q * 16 + (lane & 15);
    const int kbase = (lane >> 4) << 4;
    const int gslot = (wm * 4 + (lane >> 4)) * RSTR + wn * 64 + (lane & 15);

    for (int tt = 0; tt < ntt; ++tt) {
#pragma unroll
        for (int j = 0; j < 4; ++j)
            gload_lds16(hsrc[j] + tt * 8192, Hs + ldst[j]);
        __syncthreads();    // Hs ready (also fences prev red reads before next writes)
        f32x4 acc[4][4];
        const f32x4 zero = {0.f, 0.f, 0.f, 0.f};
#pragma unroll
        for (int i = 0; i < 4; ++i)
#pragma unroll
            for (int j = 0; j < 4; ++j) acc[i][j] = zero;
#pragma unroll
        for (int kk = 0; kk < 2; ++kk) {
            const int kbyte = kk * 64 + kbase;
            short8 b[4];
#pragma unroll
            for (int ni = 0; ni < 4; ++ni)
                b[ni] = *(const short8*)(Hs + brow[ni] * 128 + (kbyte ^ ((brow[ni] & 7) << 4)));
#pragma unroll
            for (int mi = 0; mi < 4; ++mi)
#pragma unroll
                for (int ni = 0; ni < 4; ++ni)
                    acc[mi][ni] = __builtin_amdgcn_mfma_f32_16x16x32_bf16(a[kk][mi], b[ni], acc[mi][ni], 0, 0, 0);
        }
#pragma unroll
        for (int ni = 0; ni < 4; ++ni)
            red[gslot + ni * 16] = sum16p(acc, ni, bvv);
        __syncthreads();    // red ready; all waves done reading Hs
        if (tid < 128) {
            float s = 0.f;
#pragma unroll
            for (int g = 0; g < 8; ++g) s += red[g * RSTR + tid];
            atomicAdd(&pT[tt * 128 + tid], s);
        }
        // next red write is after the NEXT stage barrier -> single buffer safe
    }
}

// ---------- kernel 4: FUSED head + tails, TYPE-INTERLEAVED schedule ----------
#define NSLOT 435
template<bool PRE>
__global__ __launch_bounds__(256)
void fused_lse(const unsigned short* __restrict__ Whb,   // [20096][1024] unified
               const float* __restrict__ W_head, const float* __restrict__ W_clu,
               const float* __restrict__ W1,
               const float* __restrict__ W2, const float* __restrict__ W3,
               const float* __restrict__ b_head, const float* __restrict__ b_clu,
               const float* __restrict__ b1, const float* __restrict__ b2,
               const float* __restrict__ b3,
               const unsigned short* __restrict__ hbf,
               const unsigned short* __restrict__ Hc1,
               const unsigned short* __restrict__ Hc2,
               const unsigned short* __restrict__ Hc3,
               const int* __restrict__ cnt,
               float* __restrict__ pT) {                 // [4][1024] zeroed totals
    __shared__ __align__(16) char smem[37888];
    char* Ws = smem;
    char* Hs = smem + 16384;
    float* bias_s = (float*)(smem + 32768);
    float* red    = (float*)(smem + 33280);   // [8][RSTR] = 4608B
    const int b = blockIdx.x;
    const int x = b & 7;
    const int i = b >> 3;
    const int m = i % 5, j = i / 5;

    if (m == 0 || m == 2) {
        const int h = 2 * j + (m >> 1);
        if (h >= 160) return;
        const int nt = x * 20 + (h >> 3);
        const int tt = h & 7;
        if (nt >= 157) return;
        if (PRE)
            gemm_lse_dev<true>(Ws, Hs, bias_s, red,
                               Whb, nullptr, nullptr,
                               20096, 20000, 20003, 1024, 1024, 16,
                               b_head, b_clu, hbf, tt * 128, nt * 128, pT);
        else
            gemm_lse_dev<false>(Ws, Hs, bias_s, red,
                                nullptr, W_head, W_clu,
                                20000, 20000, 20003, 1024, 1024, 16,
                                b_head, b_clu, hbf, tt * 128, nt * 128, pT);
    } else if (m == 1 || m == 3) {
        const int v = (2 * j + ((m - 1) >> 1)) * 8 + x;
        if (v >= 1250) return;
        tail_res_dev<64>(Ws, Hs, bias_s, red, W2, 160000, b2,
                         Hc2, cnt[2], v * 128, pT + 2 * 1024);
    } else {
        if (j < 67) {
            const int v = j * 8 + x;
            if (v >= 530) return;
            tail_res_dev<16>(Ws, Hs, bias_s, red, W3, 67735, b3,
                             Hc3, cnt[3], v * 128, pT + 3 * 1024);
        } else {
            const int nt = (j - 67) * 8 + x;
            if (nt >= 157) return;
            const int c1 = cnt[1];
            for (int t0 = 0; t0 < c1; t0 += 128)
                gemm_lse_dev<false>(Ws, Hs, bias_s, red,
                                    nullptr, W1, nullptr,
                                    20000, 20000, 20000, 256, 256, 4,
                                    b1, nullptr, Hc1, t0, nt * 128, pT + 1 * 1024);
        }
    }
}

// ---------- kernel 5: finalize (gather + assemble; reads atomic totals) ----------
__global__ void finalize(const float* __restrict__ hidden, const int* __restrict__ target,
                         const float* __restrict__ W_head, const float* __restrict__ b_head,
                         const float* __restrict__ W_clu, const float* __restrict__ b_clu,
                         const float* __restrict__ W1, const float* __restrict__ b1,
                         const float* __restrict__ W2, const float* __restrict__ b2,
                         const float* __restrict__ W3, const float* __restrict__ b3,
                         const unsigned short* __restrict__ Hc1,
                         const unsigned short* __restrict__ Hc2,
                         const unsigned short* __restrict__ Hc3,
                         const int* __restrict__ slotc,
                         const float* __restrict__ pT,    // [4][1024]
                         float* __restrict__ out) {
    const int t = blockIdx.x;
    const int lane = threadIdx.x;
    const int tgt = target[t];
    const int cid = (tgt >= 20000) + (tgt >= 40000) + (tgt >= 200000);
    const int slot = slotc[t] & 0xFFFF;

    float lse0 = LN2 * log2f(pT[t]);
    float lsec = (cid > 0) ? LN2 * log2f(pT[cid * 1024 + slot]) : 0.f;

    const int j = (cid == 0) ? tgt : (20003 - cid);
    const float* wr = (j < 20000) ? (W_head + (size_t)j * 1024)
                                  : (W_clu + (size_t)(j - 20000) * 1024);
    float acc = 0.f;
#pragma unroll
    for (int i = 0; i < 4; ++i) {
        int k4 = lane + i * 64;
        float4 h = *(const float4*)(hidden + (size_t)t * 1024 + k4 * 4);
        float4 w = *(const float4*)(wr + k4 * 4);
        acc += h.x * w.x + h.y * w.y + h.z * w.z + h.w * w.w;
    }
#pragma unroll
    for (int msk = 1; msk < 64; msk <<= 1) acc += __shfl_xor(acc, msk, 64);
    float bj = (j < 20000) ? b_head[j] : b_clu[j - 20000];
    float res = (acc + bj) - lse0;
    if (cid > 0) {
        const int starts[4] = {0, 20000, 40000, 200000};
        const int dims[4]   = {0, 256, 64, 16};
        const float* Wt = (cid == 1) ? W1 : (cid == 2) ? W2 : W3;
        const float* bt = (cid == 1) ? b1 : (cid == 2) ? b2 : b3;
        const unsigned short* pr = (cid == 1) ? Hc1 + (size_t)slot * 256
                                 : (cid == 2) ? Hc2 + (size_t)slot * 64
                                              : Hc3 + (size_t)slot * 64;
        int ti = tgt - starts[cid];
        int d  = dims[cid];
        const float* wt = Wt + (size_t)ti * d;
        float a2 = 0.f;
        for (int k = lane; k < d; k += 64) a2 += bf2f(pr[k]) * wt[k];
#pragma unroll
        for (int msk = 1; msk < 64; msk <<= 1) a2 += __shfl_xor(a2, msk, 64);
        res += (a2 + bt[ti]) - lsec;
    }
    if (lane == 0) out[t] = -res;
}

// ---------- launch ----------
extern "C" void kernel_launch(void* const* d_in, const int* in_sizes, int n_in,
                              void* d_out, int out_size, void* d_ws, size_t ws_size,
                              hipStream_t stream) {
    const float* hidden = (const float*)d_in[0];
    const int*   target = (const int*)d_in[1];
    const float* W_head = (const float*)d_in[2];
    const float* b_head = (const float*)d_in[3];
    const float* W_clu  = (const float*)d_in[4];
    const float* b_clu  = (const float*)d_in[5];
    const float* P1 = (const float*)d_in[6];
    const float* W1 = (const float*)d_in[7];
    const float* b1 = (const float*)d_in[8];
    const float* P2 = (const float*)d_in[9];
    const float* W2 = (const float*)d_in[10];
    const float* b2 = (const float*)d_in[11];
    const float* P3 = (const float*)d_in[12];
    const float* W3 = (const float*)d_in[13];
    const float* b3 = (const float*)d_in[14];
    float* out = (float*)d_out;

    char* ws = (char*)d_ws;
    size_t off = 0;
    auto alloc = [&](size_t bytes) -> char* {
        char* p = ws + off;
        off += (bytes + 255) & ~(size_t)255;
        return p;
    };

    unsigned short* hbf   = (unsigned short*)alloc((size_t)1024 * 1024 * 2);
    unsigned short* Pb    = (unsigned short*)alloc((size_t)384 * 1024 * 2);
    int* cnt   = (int*)alloc(4 * 4);
    int* slotc = (int*)alloc(1024 * 4);
    unsigned short* Hc1 = (unsigned short*)alloc((size_t)1024 * 256 * 2);
    unsigned short* Hc2 = (unsigned short*)alloc((size_t)1024 * 64 * 2);
    unsigned short* Hc3 = (unsigned short*)alloc((size_t)1024 * 64 * 2);
    float* pT  = (float*)alloc((size_t)4 * 1024 * 4);
    unsigned short* Whb = (unsigned short*)alloc((size_t)20096 * 1024 * 2);  // unified + pad
    const bool pre = (off <= ws_size);

    const int nWh  = pre ? 5120000 : 0;   // W_head chunks
    const int nClu = pre ? 768 : 0;       // W_clu chunks
    const int nZp  = pre ? 23808 : 0;     // zero rows 20003..20095
    const long nChunks = (long)nWh + nClu + nZp + 360448;
    mega_convert<<<(unsigned)((nChunks + 255) / 256), 256, 0, stream>>>(
        hidden, P1, P2, P3, W_head, W_clu, hbf, Pb, Whb, nWh, nClu, nZp);
    compact_tokens<<<1, 1024, 0, stream>>>(target, cnt, slotc);
    (void)hipMemsetAsync(pT, 0, (size_t)4 * 1024 * 4, stream);
    proj_mfma<<<dim3(8, 3), 256, 0, stream>>>(hbf, Pb, slotc, Hc1, Hc2, Hc3);

    const int NB_TOT = 8 * NSLOT;   // 3480, type-interleaved
    if (pre)
        fused_lse<true><<<NB_TOT, 256, 0, stream>>>(
            Whb, W_head, W_clu, W1, W2, W3,
            b_head, b_clu, b1, b2, b3,
            hbf, Hc1, Hc2, Hc3, cnt, pT);
    else
        fused_lse<false><<<NB_TOT, 256, 0, stream>>>(
            Whb, W_head, W_clu, W1, W2, W3,
            b_head, b_clu, b1, b2, b3,
            hbf, Hc1, Hc2, Hc3, cnt, pT);

    finalize<<<1024, 64, 0, stream>>>(hidden, target,
                                      W_head, b_head, W_clu, b_clu,
                                      W1, b1, W2, b2, W3, b3,
                                      Hc1, Hc2, Hc3, slotc, pT, out);
}